// Round 2
// baseline (217.443 us; speedup 1.0000x reference)
//
#include <hip/hip_runtime.h>
#include <hip/hip_bf16.h>
#include <stdint.h>

// Problem constants (T=128, B=64, H=1024)
#define TT 128
#define BB 64
#define HH 1024
#define MM (TT * BB)          // 8192 rows of the two GEMMs
#define NLANE (BB * HH)       // 65536 scan lanes
#define DELTA 1.0e-4          // flag band; bf16 3-pass worst-tail ~6e-5 (1.7x margin) — do NOT shrink
#define F16_ONE 0x3C00        // _Float16 1.0

typedef __attribute__((ext_vector_type(8))) short bf16x8;
typedef __attribute__((ext_vector_type(8))) _Float16 f16x8;
typedef __attribute__((ext_vector_type(4))) float f32x4;

// async global->LDS, 16 B per lane; LDS dest = wave-uniform base + lane*16
#define GLOAD16(g, l)                                                        \
    __builtin_amdgcn_global_load_lds(                                        \
        (const __attribute__((address_space(1))) unsigned int*)(g),          \
        (__attribute__((address_space(3))) unsigned int*)(l), 16, 0, 0)

#define FENCE() __builtin_amdgcn_sched_barrier(0)

static __device__ __forceinline__ unsigned short bf16_bits(float f) {
    __hip_bfloat16 b = __float2bfloat16(f);
    return *reinterpret_cast<unsigned short*>(&b);
}
static __device__ __forceinline__ unsigned short f16_bits(float f) {
    _Float16 h = (_Float16)f;
    return *reinterpret_cast<unsigned short*>(&h);
}

// ---------------------------------------------------------------------------
// Fused prep — R11: writes K-concat layouts.
//   A2[8192][2048] = [Xhi | Xlo] per row;  B2[1024][2048] = [W1hi | W1lo].
// Same bytes as before, only addressing changed.
// ---------------------------------------------------------------------------
__global__ __launch_bounds__(256) void prep_fused(const float* __restrict__ x,
                                                  const float* __restrict__ W1,
                                                  const float* __restrict__ W2,
                                                  unsigned short* __restrict__ A2,
                                                  unsigned short* __restrict__ B2,
                                                  unsigned short* __restrict__ w2h,
                                                  int* __restrict__ cnt) {
    const int bid = blockIdx.x;
    if (bid == 0 && threadIdx.x == 0) *cnt = 0;

    if (bid < 9216) {
        const bool isX = (bid < 8192);
        const int i = (isX ? bid : bid - 8192) * 256 + threadIdx.x;
        const float4 v4 = reinterpret_cast<const float4*>(isX ? x : W1)[i];
        float v[4] = {v4.x, v4.y, v4.z, v4.w};
        unsigned short hb[4], lb[4];
#pragma unroll
        for (int c = 0; c < 4; c++) {
            hb[c] = bf16_bits(v[c]);
            __hip_bfloat16 hh = *reinterpret_cast<__hip_bfloat16*>(&hb[c]);
            lb[c] = bf16_bits(v[c] - __bfloat162float(hh));
        }
        ushort4* dst = reinterpret_cast<ushort4*>(isX ? A2 : B2);
        const int r = i >> 8;          // row (1024 cols = 256 ushort4)
        const int c4 = i & 255;
        dst[(size_t)r * 512 + c4]       = make_ushort4(hb[0], hb[1], hb[2], hb[3]);
        dst[(size_t)r * 512 + 256 + c4] = make_ushort4(lb[0], lb[1], lb[2], lb[3]);
    } else {
        const int i = (bid - 9216) * 256 + threadIdx.x;
        const float4 v4 = reinterpret_cast<const float4*>(W2)[i];
        float v[4] = {v4.x, v4.y, v4.z, v4.w};
        unsigned short hb[4];
#pragma unroll
        for (int c = 0; c < 4; c++) hb[c] = f16_bits(v[c]);
        reinterpret_cast<ushort4*>(w2h)[i] = make_ushort4(hb[0], hb[1], hb[2], hb[3]);
    }
}

// ---------------------------------------------------------------------------
// GEMM1 — R11 rewrite: deep-pipelined counted-vmcnt schedule (T2+T3+T4+T5).
// Virtual K=3072 over A2/B2 concat layouts (== 3-pass split-bf16).
// Tile 256x128, 512 thr (8 waves 2Mx4N), 48 K-tiles of BK=64,
// 2 phases/tile x 16 MFMA, LDS XOR-swizzle (slot^=row&7), vmcnt(6) never 0.
// Staging plan (dead-region safe, derived):
//   tile w: {B b0,b1 + A q0,q2} issued at (w-2).P2 ; {A q1,q3} at (w-1).P1.
// Tail stages (t>=48) read harmless in-bounds bytes into dead buffers so the
// vmcnt counting stays uniform.
// ---------------------------------------------------------------------------
__global__ __launch_bounds__(512, 2) void gemm1_8ph(const unsigned short* __restrict__ A2,
                                                    const unsigned short* __restrict__ B2,
                                                    float* __restrict__ C) {
    __shared__ short As_[2][256 * 64];   // 64 KB
    __shared__ short Bs_[2][128 * 64];   // 32 KB

    const int tid = threadIdx.x;
    const int lane = tid & 63;
    const int wave = tid >> 6;       // 0..7
    const int wr = wave >> 2;        // 0..1  (M half: 128 rows)
    const int wc = wave & 3;         // 0..3  (N quarter: 32 cols)

    // XCD-grouped decode: blocks with same bid%8 form one XCD group of 32
    // (m-tiles 4c..4c+3 x all 8 n) -> A-panel L2 locality.
    const int bid = blockIdx.x;
    const int orig = (bid & 7) * 32 + (bid >> 3);
    const int m0 = (orig >> 3) * 256;
    const int n0 = (orig & 7) * 128;

    const int rsel = lane & 15;
    const int part = lane >> 4;      // 0..3

    // fragment LDS addresses (shorts), buffer-relative; row = 64 shorts = 8
    // slots of 16B; swizzle: slot' = slot ^ (row & 7)
    int adrA[8][2], adrB[2][2];
#pragma unroll
    for (int mi = 0; mi < 8; mi++) {
        const int ra = wr * 128 + mi * 16 + rsel;
#pragma unroll
        for (int ks = 0; ks < 2; ks++) {
            const int slot = ks * 4 + part;
            adrA[mi][ks] = ra * 64 + ((slot ^ (ra & 7)) << 3);
        }
    }
#pragma unroll
    for (int ni = 0; ni < 2; ni++) {
        const int rb = wc * 32 + ni * 16 + rsel;
#pragma unroll
        for (int ks = 0; ks < 2; ks++) {
            const int slot = ks * 4 + part;
            adrB[ni][ks] = rb * 64 + ((slot ^ (rb & 7)) << 3);
        }
    }

    // staging geometry: one 8KB chunk (64 rows x 128B) per GLOAD16 call;
    // global source pre-swizzled so LDS stays linear.
    const int srow = tid >> 3;                    // 0..63
    const int gslot8 = ((tid & 7) ^ (srow & 7)) << 3;
    const int ldso = wave * 512;                  // wave-uniform LDS offset (shorts)

#define STAGE_A(buf, q, kcol)                                                     \
    GLOAD16(&A2[(size_t)(m0 + (q) * 64 + srow) * 2048 + (kcol) + gslot8],         \
            &As_[buf][(q) * 4096 + ldso])
#define STAGE_B(buf, b, kcol)                                                     \
    GLOAD16(&B2[(size_t)(n0 + (b) * 64 + srow) * 2048 + (kcol) + gslot8],         \
            &Bs_[buf][(b) * 4096 + ldso])

    // k -> concat-column maps (per 64-wide tile, uniform within a tile)
#define KA_OF(t) (((t) < 16) ? (t) * 64 : (t) * 64 - 1024)
#define KB_OF(t) (((t) < 32) ? (t) * 64 : (t) * 64 - 2048)

    // ---- prologue: 10 issues, order matters for vmcnt counting ----
    STAGE_A(0, 0, 0); STAGE_A(0, 2, 0);
    STAGE_B(0, 0, 0); STAGE_B(0, 1, 0);
    STAGE_A(0, 1, 0); STAGE_A(0, 3, 0);
    STAGE_B(1, 0, 64); STAGE_B(1, 1, 64);
    STAGE_A(1, 0, 64); STAGE_A(1, 2, 64);
    asm volatile("s_waitcnt vmcnt(6)" ::: "memory");   // first 4 landed: A0 q0,q2 + B0
    FENCE();
    __builtin_amdgcn_s_barrier();
    FENCE();

    f32x4 acc[8][2] = {};

    for (int t = 0; t < 48; ++t) {
        const short* As = As_[t & 1];
        const short* Bs = Bs_[t & 1];
        const int t1 = t + 1, t2 = t + 2;
        const int kA1 = KA_OF(t1);
        const int kA2 = KA_OF(t2);
        const int kB2 = KB_OF(t2);

        bf16x8 a[4][2], b[2][2];

        // ---------------- P1: mi 0-3 (A q0/q2) x all ni ----------------
#pragma unroll
        for (int mi = 0; mi < 4; mi++)
#pragma unroll
            for (int ks = 0; ks < 2; ks++)
                a[mi][ks] = *reinterpret_cast<const bf16x8*>(&As[adrA[mi][ks]]);
#pragma unroll
        for (int ni = 0; ni < 2; ni++)
#pragma unroll
            for (int ks = 0; ks < 2; ks++)
                b[ni][ks] = *reinterpret_cast<const bf16x8*>(&Bs[adrB[ni][ks]]);
        STAGE_A((t1 & 1), 1, kA1);
        STAGE_A((t1 & 1), 3, kA1);
        FENCE();
        __builtin_amdgcn_s_barrier();
        FENCE();
        __builtin_amdgcn_s_setprio(1);
#pragma unroll
        for (int mi = 0; mi < 4; mi++)
#pragma unroll
            for (int ni = 0; ni < 2; ni++) {
                acc[mi][ni] = __builtin_amdgcn_mfma_f32_16x16x32_bf16(a[mi][0], b[ni][0], acc[mi][ni], 0, 0, 0);
                acc[mi][ni] = __builtin_amdgcn_mfma_f32_16x16x32_bf16(a[mi][1], b[ni][1], acc[mi][ni], 0, 0, 0);
            }
        __builtin_amdgcn_s_setprio(0);
        asm volatile("s_waitcnt vmcnt(6)" ::: "memory");  // confirms A(t) q1,q3
        FENCE();
        __builtin_amdgcn_s_barrier();
        FENCE();

        // ---------------- P2: mi 4-7 (A q1/q3) x all ni ----------------
#pragma unroll
        for (int mi = 0; mi < 4; mi++)
#pragma unroll
            for (int ks = 0; ks < 2; ks++)
                a[mi][ks] = *reinterpret_cast<const bf16x8*>(&As[adrA[mi + 4][ks]]);
        STAGE_B((t & 1), 0, kB2);
        STAGE_B((t & 1), 1, kB2);
        STAGE_A((t & 1), 0, kA2);
        STAGE_A((t & 1), 2, kA2);
        FENCE();
        __builtin_amdgcn_s_barrier();
        FENCE();
        __builtin_amdgcn_s_setprio(1);
#pragma unroll
        for (int mi = 0; mi < 4; mi++)
#pragma unroll
            for (int ni = 0; ni < 2; ni++) {
                acc[mi + 4][ni] = __builtin_amdgcn_mfma_f32_16x16x32_bf16(a[mi][0], b[ni][0], acc[mi + 4][ni], 0, 0, 0);
                acc[mi + 4][ni] = __builtin_amdgcn_mfma_f32_16x16x32_bf16(a[mi][1], b[ni][1], acc[mi + 4][ni], 0, 0, 0);
            }
        __builtin_amdgcn_s_setprio(0);
        asm volatile("s_waitcnt vmcnt(6)" ::: "memory");  // confirms B(t+1) + A(t+1) q0,q2
        FENCE();
        __builtin_amdgcn_s_barrier();
        FENCE();
    }
#undef STAGE_A
#undef STAGE_B

    // ---- epilogue: C write (verified 16x16 C/D layout: col=lane&15, row=(lane>>4)*4+r)
    const int col = lane & 15;
    const int quad = lane >> 4;
#pragma unroll
    for (int mi = 0; mi < 8; mi++)
#pragma unroll
        for (int ni = 0; ni < 2; ni++) {
            const int m = m0 + wr * 128 + mi * 16 + quad * 4;
            const int n = n0 + wc * 32 + ni * 16 + col;
            float* dst = &C[(size_t)m * HH + n];
#pragma unroll
            for (int r = 0; r < 4; r++)
                dst[(size_t)r * HH] = acc[mi][ni][r];
        }
}

// ---------------------------------------------------------------------------
// LIF scan — unchanged.
// ---------------------------------------------------------------------------
__global__ __launch_bounds__(256) void lif_scan_flag(const float* __restrict__ xp,
                                                     unsigned short* __restrict__ sp,
                                                     int* __restrict__ count,
                                                     int* __restrict__ list) {
    const int idx = blockIdx.x * 256 + threadIdx.x;
    double v = 0.0;
    bool flg = false;
#pragma unroll 4
    for (int t = 0; t < TT; t++) {
        const double x = (double)xp[(size_t)t * NLANE + idx];
        const double h = v + (x - v) * 0.5;
        const bool s = (h >= 1.0);
        flg |= (fabs(h - 1.0) < DELTA);
        v = s ? 0.0 : h;
        sp[(size_t)t * NLANE + idx] = s ? (unsigned short)F16_ONE : (unsigned short)0;
    }
    if (flg) {
        const int i = atomicAdd(count, 1);
        list[i] = idx;
    }
}

// ---------------------------------------------------------------------------
// Fused exact-recompute — unchanged.
// ---------------------------------------------------------------------------
__global__ __launch_bounds__(1024) void recompute_fused(const float* __restrict__ X,
                                                        const float* __restrict__ W1,
                                                        const int* __restrict__ count,
                                                        const int* __restrict__ list,
                                                        unsigned short* __restrict__ sp) {
    __shared__ double hbuf[TT];
    const int cnt = *count;
    const int wv = threadIdx.x >> 6;   // 0..15
    const int ln = threadIdx.x & 63;

    for (int li = blockIdx.x; li < cnt; li += gridDim.x) {
        const int lane = list[li];
        const int b = lane >> 10;
        const int h = lane & (HH - 1);
        const float4* w4 = reinterpret_cast<const float4*>(W1 + (size_t)h * HH);

        for (int t = wv; t < TT; t += 16) {
            const float4* x4 = reinterpret_cast<const float4*>(X + (size_t)(t * BB + b) * HH);
            double s0 = 0.0, s1 = 0.0, s2 = 0.0, s3 = 0.0;
#pragma unroll
            for (int i = 0; i < 4; i++) {
                const float4 xa = x4[ln + i * 64];
                const float4 wa = w4[ln + i * 64];
                s0 = fma((double)xa.x, (double)wa.x, s0);
                s1 = fma((double)xa.y, (double)wa.y, s1);
                s2 = fma((double)xa.z, (double)wa.z, s2);
                s3 = fma((double)xa.w, (double)wa.w, s3);
            }
            double s = (s0 + s1) + (s2 + s3);
#pragma unroll
            for (int off = 32; off >= 1; off >>= 1)
                s += __shfl_down(s, off);
            if (ln == 0) hbuf[t] = s;
        }
        __syncthreads();

        if (threadIdx.x == 0) {
            double v = 0.0;
            for (int t = 0; t < TT; t++) {
                const double hh = v + (hbuf[t] - v) * 0.5;
                const bool s = (hh >= 1.0);
                v = s ? 0.0 : hh;
                sp[(size_t)t * NLANE + lane] = s ? (unsigned short)F16_ONE : (unsigned short)0;
            }
        }
        __syncthreads();
    }
}

// ---------------------------------------------------------------------------
// GEMM2 — unchanged (128x64 tile, grid-transposed for S m-tile L2 reuse).
// ---------------------------------------------------------------------------
__global__ __launch_bounds__(256) void gemm2_mfma(const unsigned short* __restrict__ S,
                                                  const unsigned short* __restrict__ W,
                                                  float* __restrict__ O) {
    __shared__ short As[128 * 32];   // 8 KB
    __shared__ short Bs[64 * 32];    // 4 KB

    const int tid = threadIdx.x;
    const int lane = tid & 63;
    const int wave = tid >> 6;
    const int m0 = blockIdx.y * 128;   // 64 blocks in M (slow axis)
    const int n0 = blockIdx.x * 64;    // 16 blocks in N (fast axis)
    const int wm = (wave >> 1) * 64;   // {0,64}
    const int wn = (wave & 1) * 32;    // {0,32}

    const int rsel = lane & 15;
    const int part = lane >> 4;

    int adrA[4], adrB[2];
#pragma unroll
    for (int i = 0; i < 4; i++) {
        const int ra = wm + i * 16 + rsel;
        adrA[i] = ra * 32 + (part ^ ((ra >> 1) & 3)) * 8;
    }
#pragma unroll
    for (int i = 0; i < 2; i++) {
        const int rb = wn + i * 16 + rsel;
        adrB[i] = rb * 32 + (part ^ ((rb >> 1) & 3)) * 8;
    }

    f32x4 acc[4][2] = {};

    for (int k0 = 0; k0 < HH; k0 += 32) {
        // 768 chunks: A = 0..511, B = 512..767; wave-uniform sides (64 | 256)
#pragma unroll
        for (int p = 0; p < 3; p++) {
            const int c = tid + p * 256;
            const int cb = wave * 64 + p * 256;
            if (c < 512) {
                const int row = c >> 2;
                const int pslot = c & 3;
                const int pdata = pslot ^ ((row >> 1) & 3);
                GLOAD16(&S[(size_t)(m0 + row) * HH + k0 + pdata * 8], &As[cb * 8]);
            } else {
                const int c2 = c - 512;
                const int row = c2 >> 2;
                const int pslot = c2 & 3;
                const int pdata = pslot ^ ((row >> 1) & 3);
                GLOAD16(&W[(size_t)(n0 + row) * HH + k0 + pdata * 8], &Bs[(cb - 512) * 8]);
            }
        }
        __syncthreads();

        f16x8 a[4], b[2];
#pragma unroll
        for (int mi = 0; mi < 4; mi++)
            a[mi] = *reinterpret_cast<f16x8*>(&As[adrA[mi]]);
#pragma unroll
        for (int ni = 0; ni < 2; ni++)
            b[ni] = *reinterpret_cast<f16x8*>(&Bs[adrB[ni]]);

#pragma unroll
        for (int mi = 0; mi < 4; mi++)
#pragma unroll
            for (int ni = 0; ni < 2; ni++)
                acc[mi][ni] = __builtin_amdgcn_mfma_f32_16x16x32_f16(
                    a[mi], b[ni], acc[mi][ni], 0, 0, 0);

        __syncthreads();
    }

    const int col = lane & 15;
    const int quad = lane >> 4;
#pragma unroll
    for (int mi = 0; mi < 4; mi++)
#pragma unroll
        for (int ni = 0; ni < 2; ni++) {
            const int m = m0 + wm + mi * 16 + quad * 4;
            const int n = n0 + wn + ni * 16 + col;
            float* dst = &O[(size_t)m * HH + n];
#pragma unroll
            for (int r = 0; r < 4; r++)
                dst[(size_t)r * HH] = acc[mi][ni][r];
        }
}

// ---------------------------------------------------------------------------
// Launch (5 dispatches)
// ---------------------------------------------------------------------------
extern "C" void kernel_launch(void* const* d_in, const int* in_sizes, int n_in,
                              void* d_out, int out_size, void* d_ws, size_t ws_size,
                              hipStream_t stream) {
    const float* x  = (const float*)d_in[0];
    const float* W1 = (const float*)d_in[1];
    const float* W2 = (const float*)d_in[2];
    float* out = (float*)d_out;

    char* ws = (char*)d_ws;

    unsigned short* A2   = (unsigned short*)ws;                 // 33.55 MB  [Xhi|Xlo] 8192x2048
    unsigned short* B2   = A2 + (size_t)MM * 2048;              //  4.19 MB  [W1hi|W1lo] 1024x2048
    unsigned short* w2h  = B2 + (size_t)HH * 2048;              //  2.10 MB
    int*            list = (int*)(w2h + (size_t)HH * HH);       // 256 KB
    int*            cnt  = list + NLANE;                        // 4 B
    float*          xp   = (float*)(((uintptr_t)(cnt + 64) + 255) & ~(uintptr_t)255); // 33.55 MB
    unsigned short* sp   = (unsigned short*)ws;  // overlay: spikes reuse A2 after gemm1

    prep_fused<<<10240, 256, 0, stream>>>(x, W1, W2, A2, B2, w2h, cnt);

    gemm1_8ph<<<256, 512, 0, stream>>>(A2, B2, xp);

    lif_scan_flag<<<NLANE / 256, 256, 0, stream>>>(xp, sp, cnt, list);

    recompute_fused<<<512, 1024, 0, stream>>>(x, W1, cnt, list, sp);

    dim3 g2(HH / 64, MM / 128);   // x = N (fast): 16 consecutive blocks share an S m-tile
    gemm2_mfma<<<g2, 256, 0, stream>>>(sp, w2h, out);
}

// Round 3
// 214.564 us; speedup vs baseline: 1.0134x; 1.0134x over previous
//
#include <hip/hip_runtime.h>
#include <hip/hip_bf16.h>
#include <stdint.h>

// Problem constants (T=128, B=64, H=1024)
#define TT 128
#define BB 64
#define HH 1024
#define MM (TT * BB)          // 8192 rows of the two GEMMs
#define NLANE (BB * HH)       // 65536 scan lanes
#define DELTA 1.0e-4          // flag band; bf16 3-pass worst-tail ~6e-5 (1.7x margin) — do NOT shrink
#define F16_ONE 0x3C00        // _Float16 1.0

typedef __attribute__((ext_vector_type(8))) short bf16x8;
typedef __attribute__((ext_vector_type(8))) _Float16 f16x8;
typedef __attribute__((ext_vector_type(4))) float f32x4;

// async global->LDS, 16 B per lane; LDS dest = wave-uniform base + lane*16
#define GLOAD16(g, l)                                                        \
    __builtin_amdgcn_global_load_lds(                                        \
        (const __attribute__((address_space(1))) unsigned int*)(g),          \
        (__attribute__((address_space(3))) unsigned int*)(l), 16, 0, 0)

#define FENCE() __builtin_amdgcn_sched_barrier(0)

static __device__ __forceinline__ unsigned short bf16_bits(float f) {
    __hip_bfloat16 b = __float2bfloat16(f);
    return *reinterpret_cast<unsigned short*>(&b);
}
static __device__ __forceinline__ unsigned short f16_bits(float f) {
    _Float16 h = (_Float16)f;
    return *reinterpret_cast<unsigned short*>(&h);
}

// ---------------------------------------------------------------------------
// Fused prep — writes K-concat layouts.
//   A2[8192][2048] = [Xhi | Xlo] per row;  B2[1024][2048] = [W1hi | W1lo].
// ---------------------------------------------------------------------------
__global__ __launch_bounds__(256) void prep_fused(const float* __restrict__ x,
                                                  const float* __restrict__ W1,
                                                  const float* __restrict__ W2,
                                                  unsigned short* __restrict__ A2,
                                                  unsigned short* __restrict__ B2,
                                                  unsigned short* __restrict__ w2h,
                                                  int* __restrict__ cnt) {
    const int bid = blockIdx.x;
    if (bid == 0 && threadIdx.x == 0) *cnt = 0;

    if (bid < 9216) {
        const bool isX = (bid < 8192);
        const int i = (isX ? bid : bid - 8192) * 256 + threadIdx.x;
        const float4 v4 = reinterpret_cast<const float4*>(isX ? x : W1)[i];
        float v[4] = {v4.x, v4.y, v4.z, v4.w};
        unsigned short hb[4], lb[4];
#pragma unroll
        for (int c = 0; c < 4; c++) {
            hb[c] = bf16_bits(v[c]);
            __hip_bfloat16 hh = *reinterpret_cast<__hip_bfloat16*>(&hb[c]);
            lb[c] = bf16_bits(v[c] - __bfloat162float(hh));
        }
        ushort4* dst = reinterpret_cast<ushort4*>(isX ? A2 : B2);
        const int r = i >> 8;          // row (1024 cols = 256 ushort4)
        const int c4 = i & 255;
        dst[(size_t)r * 512 + c4]       = make_ushort4(hb[0], hb[1], hb[2], hb[3]);
        dst[(size_t)r * 512 + 256 + c4] = make_ushort4(lb[0], lb[1], lb[2], lb[3]);
    } else {
        const int i = (bid - 9216) * 256 + threadIdx.x;
        const float4 v4 = reinterpret_cast<const float4*>(W2)[i];
        float v[4] = {v4.x, v4.y, v4.z, v4.w};
        unsigned short hb[4];
#pragma unroll
        for (int c = 0; c < 4; c++) hb[c] = f16_bits(v[c]);
        reinterpret_cast<ushort4*>(w2h)[i] = make_ushort4(hb[0], hb[1], hb[2], hb[3]);
    }
}

// ---------------------------------------------------------------------------
// GEMM1 — R12: triple-buffered LDS, 64x64 wave tiles (4Mx2N), ONE barrier +
// ONE vmcnt(6) per K-tile.  Rationale (R11 post-mortem): kernel was
// LDS-read-BW-bound (160 b128/tile/CU = 1920cy vs 1033cy MFMA).  This layout
// cuts reads to 128/tile and removes 3 of 4 barriers.
//   - virtual K=3072 over A2/B2 concat (== 3-pass split-bf16), 48 tiles BK=64
//   - stages for tile t+2 target buf (t+2)%3 == buf of tile t-1, whose
//     readers all finished before the end-of-(t-1) barrier -> no intra-tile
//     hazard, phases need no barrier between them.
//   - ledger: prologue 12 issues, vmcnt(6) => tile0 landed.  Per tile: +6
//     issues; end-of-tile vmcnt(6) drains exactly tile t+1's 6.
// ---------------------------------------------------------------------------
__global__ __launch_bounds__(512, 2) void gemm1_tb(const unsigned short* __restrict__ A2,
                                                   const unsigned short* __restrict__ B2,
                                                   float* __restrict__ C) {
    __shared__ short As_[3][256 * 64];   // 96 KB
    __shared__ short Bs_[3][128 * 64];   // 48 KB

    const int tid = threadIdx.x;
    const int lane = tid & 63;
    const int wave = tid >> 6;       // 0..7
    const int wr = wave >> 1;        // 0..3  (M quarter: 64 rows)
    const int wc = wave & 1;         // 0..1  (N half: 64 cols)

    // XCD-grouped decode: blocks with same bid%8 form one XCD group of 32.
    const int bid = blockIdx.x;
    const int orig = (bid & 7) * 32 + (bid >> 3);
    const int m0 = (orig >> 3) * 256;
    const int n0 = (orig & 7) * 128;

    const int rsel = lane & 15;
    const int part = lane >> 4;      // 0..3

    // fragment LDS addresses (shorts), buffer-relative; row = 64 shorts = 8
    // slots of 16B; swizzle: slot' = slot ^ (row & 7)  (max 2-way bank alias)
    int adrA[4][2], adrB[4][2];
#pragma unroll
    for (int mi = 0; mi < 4; mi++) {
        const int ra = wr * 64 + mi * 16 + rsel;
#pragma unroll
        for (int ks = 0; ks < 2; ks++) {
            const int slot = ks * 4 + part;
            adrA[mi][ks] = ra * 64 + ((slot ^ (ra & 7)) << 3);
        }
    }
#pragma unroll
    for (int ni = 0; ni < 4; ni++) {
        const int rb = wc * 64 + ni * 16 + rsel;
#pragma unroll
        for (int ks = 0; ks < 2; ks++) {
            const int slot = ks * 4 + part;
            adrB[ni][ks] = rb * 64 + ((slot ^ (rb & 7)) << 3);
        }
    }

    // staging: one 8KB chunk (64 rows x 128B) per GLOAD16; global source
    // pre-swizzled so LDS write stays linear.
    const int srow = tid >> 3;                    // 0..63
    const int gslot8 = ((tid & 7) ^ (srow & 7)) << 3;
    const int ldso = wave * 512;                  // wave-uniform (shorts)

#define STAGE_A(buf, q, kcol)                                                     \
    GLOAD16(&A2[(size_t)(m0 + (q) * 64 + srow) * 2048 + (kcol) + gslot8],         \
            &As_[buf][(q) * 4096 + ldso])
#define STAGE_B(buf, b, kcol)                                                     \
    GLOAD16(&B2[(size_t)(n0 + (b) * 64 + srow) * 2048 + (kcol) + gslot8],         \
            &Bs_[buf][(b) * 4096 + ldso])

    // k -> concat-column maps (uniform within a 64-wide tile)
#define KA_OF(t) (((t) < 16) ? (t) * 64 : (t) * 64 - 1024)
#define KB_OF(t) (((t) < 32) ? (t) * 64 : (t) * 64 - 2048)

    // ---- prologue: stage tiles 0 and 1 fully (12 issues) ----
    STAGE_A(0, 0, 0); STAGE_A(0, 1, 0); STAGE_A(0, 2, 0); STAGE_A(0, 3, 0);
    STAGE_B(0, 0, 0); STAGE_B(0, 1, 0);
    STAGE_A(1, 0, 64); STAGE_A(1, 1, 64); STAGE_A(1, 2, 64); STAGE_A(1, 3, 64);
    STAGE_B(1, 0, 64); STAGE_B(1, 1, 64);
    asm volatile("s_waitcnt vmcnt(6)" ::: "memory");   // tile 0's 6 landed
    FENCE();
    __builtin_amdgcn_s_barrier();
    FENCE();

    f32x4 acc[4][4] = {};
    int bufr = 0;   // t % 3

    for (int t = 0; t < 48; ++t) {
        const short* As = As_[bufr];
        const short* Bs = Bs_[bufr];
        int sbuf = bufr + 2; if (sbuf >= 3) sbuf -= 3;   // (t+2) % 3
        const int tc = (t + 2 < 48) ? t + 2 : 47;        // clamp tail (dead data)
        const int kA2 = KA_OF(tc);
        const int kB2 = KB_OF(tc);

        bf16x8 a[4], b[4];

        // ---------------- phase ks=0 ----------------
#pragma unroll
        for (int mi = 0; mi < 4; mi++)
            a[mi] = *reinterpret_cast<const bf16x8*>(&As[adrA[mi][0]]);
#pragma unroll
        for (int ni = 0; ni < 4; ni++)
            b[ni] = *reinterpret_cast<const bf16x8*>(&Bs[adrB[ni][0]]);
        STAGE_A(sbuf, 0, kA2);
        STAGE_A(sbuf, 1, kA2);
        STAGE_B(sbuf, 0, kB2);
        __builtin_amdgcn_s_setprio(1);
#pragma unroll
        for (int mi = 0; mi < 4; mi++)
#pragma unroll
            for (int ni = 0; ni < 4; ni++)
                acc[mi][ni] = __builtin_amdgcn_mfma_f32_16x16x32_bf16(a[mi], b[ni], acc[mi][ni], 0, 0, 0);
        __builtin_amdgcn_s_setprio(0);

        // ---------------- phase ks=1 ----------------
#pragma unroll
        for (int mi = 0; mi < 4; mi++)
            a[mi] = *reinterpret_cast<const bf16x8*>(&As[adrA[mi][1]]);
#pragma unroll
        for (int ni = 0; ni < 4; ni++)
            b[ni] = *reinterpret_cast<const bf16x8*>(&Bs[adrB[ni][1]]);
        STAGE_A(sbuf, 2, kA2);
        STAGE_A(sbuf, 3, kA2);
        STAGE_B(sbuf, 1, kB2);
        __builtin_amdgcn_s_setprio(1);
#pragma unroll
        for (int mi = 0; mi < 4; mi++)
#pragma unroll
            for (int ni = 0; ni < 4; ni++)
                acc[mi][ni] = __builtin_amdgcn_mfma_f32_16x16x32_bf16(a[mi], b[ni], acc[mi][ni], 0, 0, 0);
        __builtin_amdgcn_s_setprio(0);

        // ---- one sync point per K-tile: tile t+1's 6 chunks landed ----
        asm volatile("s_waitcnt vmcnt(6)" ::: "memory");
        FENCE();
        __builtin_amdgcn_s_barrier();
        FENCE();

        bufr = (bufr == 2) ? 0 : bufr + 1;
    }
#undef STAGE_A
#undef STAGE_B

    asm volatile("s_waitcnt vmcnt(0)" ::: "memory");   // drain dead tail stages

    // ---- epilogue: C write (16x16 C/D layout: col=lane&15, row=(lane>>4)*4+r)
    const int col = lane & 15;
    const int quad = lane >> 4;
#pragma unroll
    for (int mi = 0; mi < 4; mi++)
#pragma unroll
        for (int ni = 0; ni < 4; ni++) {
            const int m = m0 + wr * 64 + mi * 16 + quad * 4;
            const int n = n0 + wc * 64 + ni * 16 + col;
            float* dst = &C[(size_t)m * HH + n];
#pragma unroll
            for (int r = 0; r < 4; r++)
                dst[(size_t)r * HH] = acc[mi][ni][r];
        }
}

// ---------------------------------------------------------------------------
// LIF scan — unchanged.
// ---------------------------------------------------------------------------
__global__ __launch_bounds__(256) void lif_scan_flag(const float* __restrict__ xp,
                                                     unsigned short* __restrict__ sp,
                                                     int* __restrict__ count,
                                                     int* __restrict__ list) {
    const int idx = blockIdx.x * 256 + threadIdx.x;
    double v = 0.0;
    bool flg = false;
#pragma unroll 4
    for (int t = 0; t < TT; t++) {
        const double x = (double)xp[(size_t)t * NLANE + idx];
        const double h = v + (x - v) * 0.5;
        const bool s = (h >= 1.0);
        flg |= (fabs(h - 1.0) < DELTA);
        v = s ? 0.0 : h;
        sp[(size_t)t * NLANE + idx] = s ? (unsigned short)F16_ONE : (unsigned short)0;
    }
    if (flg) {
        const int i = atomicAdd(count, 1);
        list[i] = idx;
    }
}

// ---------------------------------------------------------------------------
// Fused exact-recompute — unchanged.
// ---------------------------------------------------------------------------
__global__ __launch_bounds__(1024) void recompute_fused(const float* __restrict__ X,
                                                        const float* __restrict__ W1,
                                                        const int* __restrict__ count,
                                                        const int* __restrict__ list,
                                                        unsigned short* __restrict__ sp) {
    __shared__ double hbuf[TT];
    const int cnt = *count;
    const int wv = threadIdx.x >> 6;   // 0..15
    const int ln = threadIdx.x & 63;

    for (int li = blockIdx.x; li < cnt; li += gridDim.x) {
        const int lane = list[li];
        const int b = lane >> 10;
        const int h = lane & (HH - 1);
        const float4* w4 = reinterpret_cast<const float4*>(W1 + (size_t)h * HH);

        for (int t = wv; t < TT; t += 16) {
            const float4* x4 = reinterpret_cast<const float4*>(X + (size_t)(t * BB + b) * HH);
            double s0 = 0.0, s1 = 0.0, s2 = 0.0, s3 = 0.0;
#pragma unroll
            for (int i = 0; i < 4; i++) {
                const float4 xa = x4[ln + i * 64];
                const float4 wa = w4[ln + i * 64];
                s0 = fma((double)xa.x, (double)wa.x, s0);
                s1 = fma((double)xa.y, (double)wa.y, s1);
                s2 = fma((double)xa.z, (double)wa.z, s2);
                s3 = fma((double)xa.w, (double)wa.w, s3);
            }
            double s = (s0 + s1) + (s2 + s3);
#pragma unroll
            for (int off = 32; off >= 1; off >>= 1)
                s += __shfl_down(s, off);
            if (ln == 0) hbuf[t] = s;
        }
        __syncthreads();

        if (threadIdx.x == 0) {
            double v = 0.0;
            for (int t = 0; t < TT; t++) {
                const double hh = v + (hbuf[t] - v) * 0.5;
                const bool s = (hh >= 1.0);
                v = s ? 0.0 : hh;
                sp[(size_t)t * NLANE + lane] = s ? (unsigned short)F16_ONE : (unsigned short)0;
            }
        }
        __syncthreads();
    }
}

// ---------------------------------------------------------------------------
// GEMM2 — unchanged (128x64 tile, grid-transposed for S m-tile L2 reuse).
// ---------------------------------------------------------------------------
__global__ __launch_bounds__(256) void gemm2_mfma(const unsigned short* __restrict__ S,
                                                  const unsigned short* __restrict__ W,
                                                  float* __restrict__ O) {
    __shared__ short As[128 * 32];   // 8 KB
    __shared__ short Bs[64 * 32];    // 4 KB

    const int tid = threadIdx.x;
    const int lane = tid & 63;
    const int wave = tid >> 6;
    const int m0 = blockIdx.y * 128;   // 64 blocks in M (slow axis)
    const int n0 = blockIdx.x * 64;    // 16 blocks in N (fast axis)
    const int wm = (wave >> 1) * 64;   // {0,64}
    const int wn = (wave & 1) * 32;    // {0,32}

    const int rsel = lane & 15;
    const int part = lane >> 4;

    int adrA[4], adrB[2];
#pragma unroll
    for (int i = 0; i < 4; i++) {
        const int ra = wm + i * 16 + rsel;
        adrA[i] = ra * 32 + (part ^ ((ra >> 1) & 3)) * 8;
    }
#pragma unroll
    for (int i = 0; i < 2; i++) {
        const int rb = wn + i * 16 + rsel;
        adrB[i] = rb * 32 + (part ^ ((rb >> 1) & 3)) * 8;
    }

    f32x4 acc[4][2] = {};

    for (int k0 = 0; k0 < HH; k0 += 32) {
        // 768 chunks: A = 0..511, B = 512..767; wave-uniform sides (64 | 256)
#pragma unroll
        for (int p = 0; p < 3; p++) {
            const int c = tid + p * 256;
            const int cb = wave * 64 + p * 256;
            if (c < 512) {
                const int row = c >> 2;
                const int pslot = c & 3;
                const int pdata = pslot ^ ((row >> 1) & 3);
                GLOAD16(&S[(size_t)(m0 + row) * HH + k0 + pdata * 8], &As[cb * 8]);
            } else {
                const int c2 = c - 512;
                const int row = c2 >> 2;
                const int pslot = c2 & 3;
                const int pdata = pslot ^ ((row >> 1) & 3);
                GLOAD16(&W[(size_t)(n0 + row) * HH + k0 + pdata * 8], &Bs[(cb - 512) * 8]);
            }
        }
        __syncthreads();

        f16x8 a[4], b[2];
#pragma unroll
        for (int mi = 0; mi < 4; mi++)
            a[mi] = *reinterpret_cast<f16x8*>(&As[adrA[mi]]);
#pragma unroll
        for (int ni = 0; ni < 2; ni++)
            b[ni] = *reinterpret_cast<f16x8*>(&Bs[adrB[ni]]);

#pragma unroll
        for (int mi = 0; mi < 4; mi++)
#pragma unroll
            for (int ni = 0; ni < 2; ni++)
                acc[mi][ni] = __builtin_amdgcn_mfma_f32_16x16x32_f16(
                    a[mi], b[ni], acc[mi][ni], 0, 0, 0);

        __syncthreads();
    }

    const int col = lane & 15;
    const int quad = lane >> 4;
#pragma unroll
    for (int mi = 0; mi < 4; mi++)
#pragma unroll
        for (int ni = 0; ni < 2; ni++) {
            const int m = m0 + wm + mi * 16 + quad * 4;
            const int n = n0 + wn + ni * 16 + col;
            float* dst = &O[(size_t)m * HH + n];
#pragma unroll
            for (int r = 0; r < 4; r++)
                dst[(size_t)r * HH] = acc[mi][ni][r];
        }
}

// ---------------------------------------------------------------------------
// Launch (5 dispatches)
// ---------------------------------------------------------------------------
extern "C" void kernel_launch(void* const* d_in, const int* in_sizes, int n_in,
                              void* d_out, int out_size, void* d_ws, size_t ws_size,
                              hipStream_t stream) {
    const float* x  = (const float*)d_in[0];
    const float* W1 = (const float*)d_in[1];
    const float* W2 = (const float*)d_in[2];
    float* out = (float*)d_out;

    char* ws = (char*)d_ws;

    unsigned short* A2   = (unsigned short*)ws;                 // 33.55 MB  [Xhi|Xlo] 8192x2048
    unsigned short* B2   = A2 + (size_t)MM * 2048;              //  4.19 MB  [W1hi|W1lo] 1024x2048
    unsigned short* w2h  = B2 + (size_t)HH * 2048;              //  2.10 MB
    int*            list = (int*)(w2h + (size_t)HH * HH);       // 256 KB
    int*            cnt  = list + NLANE;                        // 4 B
    float*          xp   = (float*)(((uintptr_t)(cnt + 64) + 255) & ~(uintptr_t)255); // 33.55 MB
    unsigned short* sp   = (unsigned short*)ws;  // overlay: spikes reuse A2 after gemm1

    prep_fused<<<10240, 256, 0, stream>>>(x, W1, W2, A2, B2, w2h, cnt);

    gemm1_tb<<<256, 512, 0, stream>>>(A2, B2, xp);

    lif_scan_flag<<<NLANE / 256, 256, 0, stream>>>(xp, sp, cnt, list);

    recompute_fused<<<512, 1024, 0, stream>>>(x, W1, cnt, list, sp);

    dim3 g2(HH / 64, MM / 128);   // x = N (fast): 16 consecutive blocks share an S m-tile
    gemm2_mfma<<<g2, 256, 0, stream>>>(sp, w2h, out);
}